// Round 6
// baseline (7956.324 us; speedup 1.0000x reference)
//
#include <hip/hip_runtime.h>
#include <cstdint>
#include <cstddef>

// Problem constants
#define K_ 512
#define T_ 32768
#define L_STEPS 1024   // T_/32 chunks

// workspace layout (bytes) -- total ~26 MB
#define OFF_EHAT   0ul         // 512*512 fp8 = 262144
#define OFF_GPART  262144ul    // 32 f32 gold partials
#define OFF_SSCAL  262400ul    // 256 int slice scales
#define OFF_SC     263424ul    // 64 int: per-level mat scales
#define OFF_MM     263680ul    // 64 uint: per-level mat maxima (f32 bits)
#define OFF_MATS_A 1048576ul   // 32 mats * 512*512 bf16 = 16777216
#define OFF_MATS_B 17825792ul  // 16 mats bf16 = 8388608 (end 26214400)

typedef float f32x4 __attribute__((ext_vector_type(4)));
typedef int i32x8 __attribute__((ext_vector_type(8)));

#define PSTRIDE 520   // bytes per P-column row; conflict-free for b64 reads / b32 writes
#define FP8MAX 440.f  // clamp below e4m3 max(448) -> overflow saturates, never NaN

static __device__ __forceinline__ unsigned short f2bf(float x) {
  unsigned u = __float_as_uint(x);
  u += 0x7fffu + ((u >> 16) & 1u);
  return (unsigned short)(u >> 16);
}
static __device__ __forceinline__ float bf2f(unsigned short h) {
  return __uint_as_float(((unsigned)h) << 16);
}
// 32B LDS fragment via 4x ds_read_b64 (conflict-free at stride 520)
static __device__ __forceinline__ i32x8 lds_ld32(const uint8_t* p) {
  long long a = *(const long long*)p;
  long long b = *(const long long*)(p + 8);
  long long c = *(const long long*)(p + 16);
  long long d = *(const long long*)(p + 24);
  i32x8 r;
  r[0] = (int)a; r[1] = (int)(a >> 32);
  r[2] = (int)b; r[3] = (int)(b >> 32);
  r[4] = (int)c; r[5] = (int)(c >> 32);
  r[6] = (int)d; r[7] = (int)(d >> 32);
  return r;
}

// ---------------- init: zero the atomic-max slots ----------------
__global__ __launch_bounds__(64) void init_k(unsigned* __restrict__ mm) {
  mm[threadIdx.x] = 0u;
}

// ---------------- prep: Ehat = fp8_e4m3(exp(transitions)) ----------------
__global__ __launch_bounds__(512) void prep_e8_k(const float* __restrict__ tr,
                                                 uint8_t* __restrict__ Ehat) {
  int gid = blockIdx.x * 512 + threadIdx.x;
  int i2 = gid * 2;
  float a = fminf(__expf(tr[i2]), FP8MAX);
  float b = fminf(__expf(tr[i2 + 1]), FP8MAX);
  int w = __builtin_amdgcn_cvt_pk_fp8_f32(a, b, 0, false);
  *(unsigned short*)(Ehat + i2) = (unsigned short)(w & 0xffff);
}

// ---------------- gold score (exact f32, deterministic, 32 partials) ----------------
__global__ __launch_bounds__(1024) void gold_k(const float* __restrict__ obs,
                                               const int* __restrict__ tags,
                                               const float* __restrict__ tr,
                                               float* __restrict__ gpart) {
  __shared__ float red[1024];
  int i = blockIdx.x * 1024 + threadIdx.x;
  float s = 0.f;
  if (i < T_ - 1) {
    int cur = tags[i], nxt = tags[i + 1];
    s = tr[nxt * K_ + cur] + obs[(size_t)nxt * T_ + i];
  }
  red[threadIdx.x] = s;
  __syncthreads();
  for (int h = 512; h > 0; h >>= 1) {
    if ((int)threadIdx.x < h) red[threadIdx.x] += red[threadIdx.x + h];
    __syncthreads();
  }
  if (threadIdx.x == 0) gpart[blockIdx.x] = red[0];
}

// ---------------- phase 1: per-(chunk, 64-col slice) transfer matrix ----------------
// 8 waves; wave wv owns output rows 64wv..64wv+63. E fragments pinned in AGPRs.
// P slice double-buffered in LDS (stride 520), ONE barrier per step. Deferred
// power-of-2 renorm: sigma_t predicted from step t-1's realized max/growth (exact
// integer ledger); prediction errors are harmless: fminf(FP8MAX) saturates
// overflow (no e4m3 NaN encoding), undershoot only costs sub-max precision.
__global__ __launch_bounds__(512, 2)
void phase1_k(const uint8_t* __restrict__ Ehat, const float* __restrict__ obs,
              unsigned short* __restrict__ mats, int* __restrict__ sliceScales) {
  __shared__ __align__(16) uint8_t Plds[2][64 * PSTRIDE];  // 66560 B
  __shared__ float obs_lds[8][512];                        // 16384 B (exp(obs))
  __shared__ float pmax[2][512];                           // 4096 B

  const int tid = threadIdx.x;
  const int wv = tid >> 6;
  const int lane = tid & 63;
  const int l15 = lane & 15;
  const int g = lane >> 4;
  // XCD-aware remap: a chunk's 8 slices land on one XCD (shared L2 for obs)
  const int bid = blockIdx.x;
  const int chunk = 4 * (bid & 7) + (bid >> 6);
  const int slice = (bid >> 3) & 7;

  // E fragments for 16x16x128: lane holds A[row=l15][k=32g..32g+31] per (rt, kt).
  // Pin into AGPRs: asm def is opaque -> never rematerialized.
  i32x8 ef[4][4];
#pragma unroll
  for (int rt = 0; rt < 4; ++rt)
#pragma unroll
    for (int kt = 0; kt < 4; ++kt) {
      ef[rt][kt] = *(const i32x8*)(Ehat +
          ((64 * wv + 16 * rt + l15) * 512 + 128 * kt + 32 * g));
      asm volatile("" : "+a"(ef[rt][kt]));
    }

  // init P(buffer 0) = identity slice
  for (int i = tid; i < 64 * PSTRIDE / 4; i += 512) ((int*)Plds[0])[i] = 0;
  __syncthreads();
  if (tid < 64) {
    int gj = slice * 64 + tid;             // global state index of this column
    Plds[0][tid * PSTRIDE + gj] = 0x38;    // fp8 e4m3 1.0
  }
  __syncthreads();

  int accScale = 0;
  int sigPrev = 0, Sprev2 = 0;
  const int t0 = chunk * L_STEPS;

  // obs prefetch registers (8 timesteps of this thread's row)
  float4 pf0, pf1;
  {
    const float4* sp = (const float4*)(obs + (size_t)tid * T_ + t0);
    pf0 = sp[0]; pf1 = sp[1];
  }

#pragma unroll 1
  for (int tl = 0; tl < L_STEPS; ++tl) {
    if ((tl & 7) == 0) {
      // stage exp(obs) so the epilogue never runs v_exp
      obs_lds[0][tid] = __expf(pf0.x); obs_lds[1][tid] = __expf(pf0.y);
      obs_lds[2][tid] = __expf(pf0.z); obs_lds[3][tid] = __expf(pf0.w);
      obs_lds[4][tid] = __expf(pf1.x); obs_lds[5][tid] = __expf(pf1.y);
      obs_lds[6][tid] = __expf(pf1.z); obs_lds[7][tid] = __expf(pf1.w);
      __syncthreads();
      int tn = t0 + tl + 8;
      if (tn >= T_) tn = 0;               // dummy for the last block
      const float4* sp = (const float4*)(obs + (size_t)tid * T_ + tn);
      pf0 = sp[0]; pf1 = sp[1];
    }

    const uint8_t* bufR = Plds[tl & 1];
    uint8_t* bufW = Plds[(tl & 1) ^ 1];
    const uint8_t* baseR = bufR + l15 * PSTRIDE + 32 * g;

    f32x4 acc[4][4];
    // kt = 0 peeled with zero-C (no per-step acc zeroing); only ONE b-frag live
    {
      const f32x4 z = (f32x4){0.f, 0.f, 0.f, 0.f};
#pragma unroll
      for (int c = 0; c < 4; ++c) {
        i32x8 b = lds_ld32(baseR + c * (16 * PSTRIDE));
#pragma unroll
        for (int rt = 0; rt < 4; ++rt)
          acc[rt][c] = __builtin_amdgcn_mfma_scale_f32_16x16x128_f8f6f4(
              ef[rt][0], b, z, 0, 0, 0, 0x7f7f7f7f, 0, 0x7f7f7f7f);
      }
    }
#pragma unroll
    for (int kt = 1; kt < 4; ++kt)
#pragma unroll
      for (int c = 0; c < 4; ++c) {
        i32x8 b = lds_ld32(baseR + c * (16 * PSTRIDE) + 128 * kt);
#pragma unroll
        for (int rt = 0; rt < 4; ++rt)
          acc[rt][c] = __builtin_amdgcn_mfma_scale_f32_16x16x128_f8f6f4(
              ef[rt][kt], b, acc[rt][c], 0, 0, 0, 0x7f7f7f7f, 0, 0x7f7f7f7f);
      }

    // ---- deferred sigma: predict from step t-1's realized max (overlaps MFMAs) ----
    int sigma;
    if (tl == 0) {
      sigma = -13;                         // conservative bootstrap (stored max ~2^-4)
      sigPrev = sigma;
    } else {
      const float* pm = pmax[(tl & 1) ^ 1];
      float m = pm[lane];
#pragma unroll
      for (int q = 1; q < 8; ++q) m = fmaxf(m, pm[lane + (q << 6)]);
#pragma unroll
      for (int off = 1; off < 64; off <<= 1) m = fmaxf(m, __shfl_xor(m, off, 64));
      unsigned mb = __builtin_amdgcn_readfirstlane(__float_as_uint(m));
      int S1 = (int)((mb >> 23) & 255) - 127;     // stored-domain exponent S_{t-1}
      S1 = min(max(S1, -60), 60);
      // realized growth gamma_{t-1} = S_{t-1} - sigma_{t-1} - S_{t-2}
      int gam = (tl == 1) ? 16 : (S1 - sigPrev) - Sprev2;
      gam = min(max(gam, 2), 20);
      sigma = 3 - S1 - gam;                // target stored max ~2^3
      sigma = min(max(sigma, -60), 30);
      Sprev2 = S1;
      sigPrev = sigma;
    }
    accScale -= sigma;                     // TRUE = stored * 2^accScale
    float scf = __uint_as_float((unsigned)(127 + sigma) << 23);

    // ---- epilogue: v = min(acc*exp(o)*2^sigma, FP8MAX); track max; fp8 store ----
    const int tl7 = tl & 7;
    float vmax = 0.f;
#pragma unroll
    for (int rt = 0; rt < 4; ++rt) {
      float4 eo4 = *(const float4*)&obs_lds[tl7][64 * wv + 16 * rt + 4 * g];
      float e0 = eo4.x * scf, e1 = eo4.y * scf, e2 = eo4.z * scf, e3 = eo4.w * scf;
#pragma unroll
      for (int ct = 0; ct < 4; ++ct) {
        float v0 = fminf(acc[rt][ct][0] * e0, FP8MAX);
        float v1 = fminf(acc[rt][ct][1] * e1, FP8MAX);
        float v2 = fminf(acc[rt][ct][2] * e2, FP8MAX);
        float v3 = fminf(acc[rt][ct][3] * e3, FP8MAX);
        vmax = fmaxf(vmax, fmaxf(fmaxf(v0, v1), fmaxf(v2, v3)));
        int w32 = __builtin_amdgcn_cvt_pk_fp8_f32(v0, v1, 0, false);
        w32 = __builtin_amdgcn_cvt_pk_fp8_f32(v2, v3, w32, true);
        *(int*)(bufW + (16 * ct + l15) * PSTRIDE + (64 * wv + 16 * rt + 4 * g)) = w32;
      }
    }
    pmax[tl & 1][(wv << 6) + lane] = vmax;
    __syncthreads();
  }

  // write slice (bf16) to chunk matrix, row-major [i][j]; final P is in Plds[0]
  for (int cl = 0; cl < 64; ++cl) {
    float f = __builtin_amdgcn_cvt_f32_fp8((int)Plds[0][cl * PSTRIDE + tid], 0);
    mats[(size_t)chunk * 262144 + (size_t)tid * 512 + slice * 64 + cl] = f2bf(f);
  }
  if (tid == 0) sliceScales[chunk * 8 + slice] = accScale;
}

// ---------------- repair: harmonize the 8 slice scales of each chunk; record chunk max ----------------
__global__ __launch_bounds__(256) void repair_k(unsigned short* __restrict__ mats,
                                                const int* __restrict__ sliceScales,
                                                int* __restrict__ chunkScales,
                                                unsigned* __restrict__ mmL0) {
  int chunk = blockIdx.x >> 3, slice = blockIdx.x & 7;
  int smax = sliceScales[chunk * 8];
  for (int q = 1; q < 8; ++q) smax = max(smax, sliceScales[chunk * 8 + q]);
  int d = sliceScales[chunk * 8 + slice] - smax;   // <= 0
  float fac = exp2f((float)max(d, -126));
  float lmax = 0.f;
  for (int n = threadIdx.x; n < 512 * 64; n += 256) {
    int row = n >> 6, col = n & 63;
    size_t idx = (size_t)chunk * 262144 + (size_t)row * 512 + slice * 64 + col;
    float v = bf2f(mats[idx]) * fac;
    mats[idx] = f2bf(v);
    lmax = fmaxf(lmax, v);
  }
#pragma unroll
  for (int off = 1; off < 64; off <<= 1) lmax = fmaxf(lmax, __shfl_xor(lmax, off, 64));
  if ((threadIdx.x & 63) == 0) atomicMax(&mmL0[chunk], __float_as_uint(lmax));
  if (threadIdx.x == 0 && slice == 0) chunkScales[chunk] = smax;
}

// ---------------- tree: OUT[m] = IN[2m+1] * IN[2m], adaptively renormalized ----------------
__global__ __launch_bounds__(256) void tree_k(const unsigned short* __restrict__ in,
                                              unsigned short* __restrict__ out,
                                              const int* __restrict__ sIn,
                                              int* __restrict__ sOut,
                                              const unsigned* __restrict__ mmIn,
                                              unsigned* __restrict__ mmOut) {
  __shared__ float Al[64][65];
  __shared__ float Bl[64][65];
  int m = blockIdx.x >> 6;
  int t = blockIdx.x & 63;
  int i0 = (t >> 3) * 64, j0 = (t & 7) * 64;
  const unsigned short* A = in + (size_t)(2 * m + 1) * 262144;  // later chunk (left)
  const unsigned short* B = in + (size_t)(2 * m) * 262144;      // earlier chunk (right)
  int tid = threadIdx.x;
  int ty = tid >> 4, tx = tid & 15;

  int ea = (int)(mmIn[2 * m + 1] >> 23) - 127;
  int eb = (int)(mmIn[2 * m] >> 23) - 127;
  ea = max(min(ea, 60), -60); eb = max(min(eb, 60), -60);
  float norm = __uint_as_float((unsigned)(127 - ea - eb) << 23);

  float acc[4][4] = {};
#pragma unroll 1
  for (int k0 = 0; k0 < 512; k0 += 64) {
    __syncthreads();
    int r = tid >> 2, cs = (tid & 3) * 16;
    const unsigned short* ap = A + (size_t)(i0 + r) * 512 + k0 + cs;
    const unsigned short* bp = B + (size_t)(k0 + r) * 512 + j0 + cs;
#pragma unroll
    for (int q = 0; q < 16; ++q) Al[r][cs + q] = bf2f(ap[q]);
#pragma unroll
    for (int q = 0; q < 16; ++q) Bl[r][cs + q] = bf2f(bp[q]);
    __syncthreads();
#pragma unroll 8
    for (int k = 0; k < 64; ++k) {
      float av[4], bv[4];
#pragma unroll
      for (int i = 0; i < 4; ++i) av[i] = Al[ty * 4 + i][k];
#pragma unroll
      for (int j = 0; j < 4; ++j) bv[j] = Bl[k][tx * 4 + j];
#pragma unroll
      for (int i = 0; i < 4; ++i)
#pragma unroll
        for (int j = 0; j < 4; ++j) acc[i][j] += av[i] * bv[j];
    }
  }
  float lmax = 0.f;
#pragma unroll
  for (int i = 0; i < 4; ++i)
#pragma unroll
    for (int j = 0; j < 4; ++j) {
      float v = acc[i][j] * norm;
      lmax = fmaxf(lmax, v);
      out[(size_t)m * 262144 + (size_t)(i0 + ty * 4 + i) * 512 + (j0 + tx * 4 + j)] = f2bf(v);
    }
#pragma unroll
  for (int off = 1; off < 64; off <<= 1) lmax = fmaxf(lmax, __shfl_xor(lmax, off, 64));
  if ((tid & 63) == 0) atomicMax(&mmOut[m], __float_as_uint(lmax));
  if (t == 0 && tid == 0) sOut[m] = sIn[2 * m] + sIn[2 * m + 1] + ea + eb;
}

// ---------------- final: forward = log(sum P_total) + scale*ln2; out = fwd - gold ----------------
__global__ __launch_bounds__(512) void final_k(const unsigned short* __restrict__ P,
                                               const int* __restrict__ sc,
                                               const float* __restrict__ gpart,
                                               float* __restrict__ outp) {
  __shared__ float red[512];
  float s = 0.f;
  for (int i = threadIdx.x; i < 262144; i += 512) s += bf2f(P[i]);
  red[threadIdx.x] = s;
  __syncthreads();
  for (int h = 256; h > 0; h >>= 1) {
    if ((int)threadIdx.x < h) red[threadIdx.x] += red[threadIdx.x + h];
    __syncthreads();
  }
  if (threadIdx.x == 0) {
    double gold = 0.0;
    for (int q = 0; q < 32; ++q) gold += (double)gpart[q];
    double fwd = log((double)red[0]) + 0.69314718055994530942 * (double)sc[0];
    outp[0] = (float)(fwd - gold);
  }
}

extern "C" void kernel_launch(void* const* d_in, const int* in_sizes, int n_in,
                              void* d_out, int out_size, void* d_ws, size_t ws_size,
                              hipStream_t stream) {
  const float* obs = (const float*)d_in[0];   // (K, T) f32
  const int* tags = (const int*)d_in[1];      // (T,) i32
  const float* tr = (const float*)d_in[2];    // (K, K) f32
  float* out = (float*)d_out;

  uint8_t* ws = (uint8_t*)d_ws;
  uint8_t* Ehat = ws + OFF_EHAT;
  float* gpart = (float*)(ws + OFF_GPART);
  int* sliceScales = (int*)(ws + OFF_SSCAL);
  int* sc = (int*)(ws + OFF_SC);           // 64 ints, per-level
  unsigned* mm = (unsigned*)(ws + OFF_MM); // 64 uints, per-level
  unsigned short* matsA = (unsigned short*)(ws + OFF_MATS_A);
  unsigned short* matsB = (unsigned short*)(ws + OFF_MATS_B);

  hipLaunchKernelGGL(init_k, dim3(1), dim3(64), 0, stream, mm);
  hipLaunchKernelGGL(prep_e8_k, dim3(256), dim3(512), 0, stream, tr, Ehat);
  hipLaunchKernelGGL(gold_k, dim3(32), dim3(1024), 0, stream, obs, tags, tr, gpart);
  hipLaunchKernelGGL(phase1_k, dim3(256), dim3(512), 0, stream, Ehat, obs, matsA, sliceScales);
  hipLaunchKernelGGL(repair_k, dim3(256), dim3(256), 0, stream, matsA, sliceScales, sc + 0, mm + 0);
  // tree: 32 -> 16 -> 8 -> 4 -> 2 -> 1 (alternating matsA/matsB)
  hipLaunchKernelGGL(tree_k, dim3(16 * 64), dim3(256), 0, stream, matsA, matsB, sc + 0,  sc + 32, mm + 0,  mm + 32);
  hipLaunchKernelGGL(tree_k, dim3(8 * 64),  dim3(256), 0, stream, matsB, matsA, sc + 32, sc + 48, mm + 32, mm + 48);
  hipLaunchKernelGGL(tree_k, dim3(4 * 64),  dim3(256), 0, stream, matsA, matsB, sc + 48, sc + 56, mm + 48, mm + 56);
  hipLaunchKernelGGL(tree_k, dim3(2 * 64),  dim3(256), 0, stream, matsB, matsA, sc + 56, sc + 60, mm + 56, mm + 60);
  hipLaunchKernelGGL(tree_k, dim3(1 * 64),  dim3(256), 0, stream, matsA, matsB, sc + 60, sc + 62, mm + 60, mm + 62);
  hipLaunchKernelGGL(final_k, dim3(1), dim3(512), 0, stream, matsB, sc + 62, gpart, out);
}

// Round 7
// 6925.081 us; speedup vs baseline: 1.1489x; 1.1489x over previous
//
#include <hip/hip_runtime.h>
#include <cstdint>
#include <cstddef>

// Problem constants
#define K_ 512
#define T_ 32768
#define L_STEPS 1024   // T_/32 chunks

// workspace layout (bytes) -- total ~26 MB
#define OFF_EHAT   0ul         // 512*512 fp8 = 262144
#define OFF_GPART  262144ul    // 32 f32 gold partials
#define OFF_SSCAL  262400ul    // 256 int slice scales
#define OFF_SC     263424ul    // 64 int: per-level mat scales
#define OFF_MM     263680ul    // 64 uint: per-level mat maxima (f32 bits)
#define OFF_MATS_A 1048576ul   // 32 mats * 512*512 bf16 = 16777216
#define OFF_MATS_B 17825792ul  // 16 mats bf16 = 8388608 (end 26214400)

typedef float f32x4 __attribute__((ext_vector_type(4)));
typedef int i32x8 __attribute__((ext_vector_type(8)));

#define PSTRIDE 520   // bytes per P-column row; conflict-free for b64 reads / b32 writes
#define FP8MAX 440.f  // clamp below e4m3 max(448) -> overflow saturates, never NaN

static __device__ __forceinline__ unsigned short f2bf(float x) {
  unsigned u = __float_as_uint(x);
  u += 0x7fffu + ((u >> 16) & 1u);
  return (unsigned short)(u >> 16);
}
static __device__ __forceinline__ float bf2f(unsigned short h) {
  return __uint_as_float(((unsigned)h) << 16);
}
// 32B LDS fragment via 4x ds_read_b64 (conflict-free at stride 520)
static __device__ __forceinline__ i32x8 lds_ld32(const uint8_t* p) {
  long long a = *(const long long*)p;
  long long b = *(const long long*)(p + 8);
  long long c = *(const long long*)(p + 16);
  long long d = *(const long long*)(p + 24);
  i32x8 r;
  r[0] = (int)a; r[1] = (int)(a >> 32);
  r[2] = (int)b; r[3] = (int)(b >> 32);
  r[4] = (int)c; r[5] = (int)(c >> 32);
  r[6] = (int)d; r[7] = (int)(d >> 32);
  return r;
}

// ---------------- init: zero the atomic-max slots ----------------
__global__ __launch_bounds__(64) void init_k(unsigned* __restrict__ mm) {
  mm[threadIdx.x] = 0u;
}

// ---------------- prep: Ehat = fp8_e4m3(exp(transitions)) ----------------
__global__ __launch_bounds__(512) void prep_e8_k(const float* __restrict__ tr,
                                                 uint8_t* __restrict__ Ehat) {
  int gid = blockIdx.x * 512 + threadIdx.x;
  int i2 = gid * 2;
  float a = fminf(__expf(tr[i2]), FP8MAX);
  float b = fminf(__expf(tr[i2 + 1]), FP8MAX);
  int w = __builtin_amdgcn_cvt_pk_fp8_f32(a, b, 0, false);
  *(unsigned short*)(Ehat + i2) = (unsigned short)(w & 0xffff);
}

// ---------------- gold score (exact f32, deterministic, 32 partials) ----------------
__global__ __launch_bounds__(1024) void gold_k(const float* __restrict__ obs,
                                               const int* __restrict__ tags,
                                               const float* __restrict__ tr,
                                               float* __restrict__ gpart) {
  __shared__ float red[1024];
  int i = blockIdx.x * 1024 + threadIdx.x;
  float s = 0.f;
  if (i < T_ - 1) {
    int cur = tags[i], nxt = tags[i + 1];
    s = tr[nxt * K_ + cur] + obs[(size_t)nxt * T_ + i];
  }
  red[threadIdx.x] = s;
  __syncthreads();
  for (int h = 512; h > 0; h >>= 1) {
    if ((int)threadIdx.x < h) red[threadIdx.x] += red[threadIdx.x + h];
    __syncthreads();
  }
  if (threadIdx.x == 0) gpart[blockIdx.x] = red[0];
}

// ---------------- phase 1: per-(chunk, 64-col slice) transfer matrix ----------------
// 8 waves; wave wv owns output rows 64wv..64wv+63. E fragments live in registers
// (NO asm pin -- round 4 proves the allocator keeps them resident; the pin caused
// spills in round 6). P slice double-buffered in LDS (stride 520), ONE barrier per
// step. Deferred power-of-2 renorm: sigma_t predicted from step t-1's realized
// max/growth (exact integer ledger); prediction errors harmless: fminf(FP8MAX)
// saturates overflow (no e4m3 NaN), undershoot only costs sub-max precision.
__global__ __launch_bounds__(512, 2)
void phase1_k(const uint8_t* __restrict__ Ehat, const float* __restrict__ obs,
              unsigned short* __restrict__ mats, int* __restrict__ sliceScales) {
  __shared__ __align__(16) uint8_t Plds[2][64 * PSTRIDE];  // 66560 B
  __shared__ float obs_lds[8][512];                        // 16384 B (exp(obs))
  __shared__ float pmax[2][512];                           // 4096 B

  const int tid = threadIdx.x;
  const int wv = tid >> 6;
  const int lane = tid & 63;
  const int l15 = lane & 15;
  const int g = lane >> 4;
  // XCD-aware remap: a chunk's 8 slices land on one XCD (shared L2 for obs)
  const int bid = blockIdx.x;
  const int chunk = 4 * (bid & 7) + (bid >> 6);
  const int slice = (bid >> 3) & 7;

  // E fragments for 16x16x128: lane holds A[row=l15][k=32g..32g+31] per (rt, kt).
  i32x8 ef[4][4];
#pragma unroll
  for (int rt = 0; rt < 4; ++rt)
#pragma unroll
    for (int kt = 0; kt < 4; ++kt)
      ef[rt][kt] = *(const i32x8*)(Ehat +
          ((64 * wv + 16 * rt + l15) * 512 + 128 * kt + 32 * g));

  // init P(buffer 0) = identity slice
  for (int i = tid; i < 64 * PSTRIDE / 4; i += 512) ((int*)Plds[0])[i] = 0;
  __syncthreads();
  if (tid < 64) {
    int gj = slice * 64 + tid;             // global state index of this column
    Plds[0][tid * PSTRIDE + gj] = 0x38;    // fp8 e4m3 1.0
  }
  __syncthreads();

  int accScale = 0;
  int sigPrev = 0, Sprev2 = 0;
  const int t0 = chunk * L_STEPS;

  // obs prefetch registers (8 timesteps of this thread's row)
  float4 pf0, pf1;
  {
    const float4* sp = (const float4*)(obs + (size_t)tid * T_ + t0);
    pf0 = sp[0]; pf1 = sp[1];
  }

#pragma unroll 1
  for (int tl = 0; tl < L_STEPS; ++tl) {
    if ((tl & 7) == 0) {
      // stage exp(obs) so the epilogue never runs v_exp
      obs_lds[0][tid] = __expf(pf0.x); obs_lds[1][tid] = __expf(pf0.y);
      obs_lds[2][tid] = __expf(pf0.z); obs_lds[3][tid] = __expf(pf0.w);
      obs_lds[4][tid] = __expf(pf1.x); obs_lds[5][tid] = __expf(pf1.y);
      obs_lds[6][tid] = __expf(pf1.z); obs_lds[7][tid] = __expf(pf1.w);
      __syncthreads();
      int tn = t0 + tl + 8;
      if (tn >= T_) tn = 0;               // dummy for the last block
      const float4* sp = (const float4*)(obs + (size_t)tid * T_ + tn);
      pf0 = sp[0]; pf1 = sp[1];
    }

    const uint8_t* bufR = Plds[tl & 1];
    uint8_t* bufW = Plds[(tl & 1) ^ 1];
    const uint8_t* baseR = bufR + l15 * PSTRIDE + 32 * g;

    f32x4 acc[4][4];
    // kt = 0 peeled with zero-C (no per-step acc zeroing); only ONE b-frag live
    {
      const f32x4 z = (f32x4){0.f, 0.f, 0.f, 0.f};
#pragma unroll
      for (int c = 0; c < 4; ++c) {
        i32x8 b = lds_ld32(baseR + c * (16 * PSTRIDE));
#pragma unroll
        for (int rt = 0; rt < 4; ++rt)
          acc[rt][c] = __builtin_amdgcn_mfma_scale_f32_16x16x128_f8f6f4(
              ef[rt][0], b, z, 0, 0, 0, 0x7f7f7f7f, 0, 0x7f7f7f7f);
      }
    }
#pragma unroll
    for (int kt = 1; kt < 4; ++kt)
#pragma unroll
      for (int c = 0; c < 4; ++c) {
        i32x8 b = lds_ld32(baseR + c * (16 * PSTRIDE) + 128 * kt);
#pragma unroll
        for (int rt = 0; rt < 4; ++rt)
          acc[rt][c] = __builtin_amdgcn_mfma_scale_f32_16x16x128_f8f6f4(
              ef[rt][kt], b, acc[rt][c], 0, 0, 0, 0x7f7f7f7f, 0, 0x7f7f7f7f);
      }

    // ---- deferred sigma: predict from step t-1's realized max (overlaps MFMAs) ----
    int sigma;
    if (tl == 0) {
      sigma = -13;                         // conservative bootstrap (stored max ~2^-4)
      sigPrev = sigma;
    } else {
      const float* pm = pmax[(tl & 1) ^ 1];
      float m = pm[lane];
#pragma unroll
      for (int q = 1; q < 8; ++q) m = fmaxf(m, pm[lane + (q << 6)]);
#pragma unroll
      for (int off = 1; off < 64; off <<= 1) m = fmaxf(m, __shfl_xor(m, off, 64));
      unsigned mb = __builtin_amdgcn_readfirstlane(__float_as_uint(m));
      int S1 = (int)((mb >> 23) & 255) - 127;     // stored-domain exponent S_{t-1}
      S1 = min(max(S1, -60), 60);
      // realized growth gamma_{t-1} = S_{t-1} - sigma_{t-1} - S_{t-2}
      int gam = (tl == 1) ? 16 : (S1 - sigPrev) - Sprev2;
      gam = min(max(gam, 2), 20);
      sigma = 3 - S1 - gam;                // target stored max ~2^3
      sigma = min(max(sigma, -60), 30);
      Sprev2 = S1;
      sigPrev = sigma;
    }
    accScale -= sigma;                     // TRUE = stored * 2^accScale
    float scf = __uint_as_float((unsigned)(127 + sigma) << 23);

    // ---- epilogue: v = min(acc*exp(o)*2^sigma, FP8MAX); track max; fp8 store ----
    const int tl7 = tl & 7;
    float vmax = 0.f;
#pragma unroll
    for (int rt = 0; rt < 4; ++rt) {
      float4 eo4 = *(const float4*)&obs_lds[tl7][64 * wv + 16 * rt + 4 * g];
      float e0 = eo4.x * scf, e1 = eo4.y * scf, e2 = eo4.z * scf, e3 = eo4.w * scf;
#pragma unroll
      for (int ct = 0; ct < 4; ++ct) {
        float v0 = fminf(acc[rt][ct][0] * e0, FP8MAX);
        float v1 = fminf(acc[rt][ct][1] * e1, FP8MAX);
        float v2 = fminf(acc[rt][ct][2] * e2, FP8MAX);
        float v3 = fminf(acc[rt][ct][3] * e3, FP8MAX);
        vmax = fmaxf(vmax, fmaxf(fmaxf(v0, v1), fmaxf(v2, v3)));
        int w32 = __builtin_amdgcn_cvt_pk_fp8_f32(v0, v1, 0, false);
        w32 = __builtin_amdgcn_cvt_pk_fp8_f32(v2, v3, w32, true);
        *(int*)(bufW + (16 * ct + l15) * PSTRIDE + (64 * wv + 16 * rt + 4 * g)) = w32;
      }
    }
    pmax[tl & 1][(wv << 6) + lane] = vmax;
    __syncthreads();
  }

  // write slice (bf16) to chunk matrix, row-major [i][j]; final P is in Plds[0]
  for (int cl = 0; cl < 64; ++cl) {
    float f = __builtin_amdgcn_cvt_f32_fp8((int)Plds[0][cl * PSTRIDE + tid], 0);
    mats[(size_t)chunk * 262144 + (size_t)tid * 512 + slice * 64 + cl] = f2bf(f);
  }
  if (tid == 0) sliceScales[chunk * 8 + slice] = accScale;
}

// ---------------- repair: harmonize the 8 slice scales of each chunk; record chunk max ----------------
__global__ __launch_bounds__(256) void repair_k(unsigned short* __restrict__ mats,
                                                const int* __restrict__ sliceScales,
                                                int* __restrict__ chunkScales,
                                                unsigned* __restrict__ mmL0) {
  int chunk = blockIdx.x >> 3, slice = blockIdx.x & 7;
  int smax = sliceScales[chunk * 8];
  for (int q = 1; q < 8; ++q) smax = max(smax, sliceScales[chunk * 8 + q]);
  int d = sliceScales[chunk * 8 + slice] - smax;   // <= 0
  float fac = exp2f((float)max(d, -126));
  float lmax = 0.f;
  for (int n = threadIdx.x; n < 512 * 64; n += 256) {
    int row = n >> 6, col = n & 63;
    size_t idx = (size_t)chunk * 262144 + (size_t)row * 512 + slice * 64 + col;
    float v = bf2f(mats[idx]) * fac;
    mats[idx] = f2bf(v);
    lmax = fmaxf(lmax, v);
  }
#pragma unroll
  for (int off = 1; off < 64; off <<= 1) lmax = fmaxf(lmax, __shfl_xor(lmax, off, 64));
  if ((threadIdx.x & 63) == 0) atomicMax(&mmL0[chunk], __float_as_uint(lmax));
  if (threadIdx.x == 0 && slice == 0) chunkScales[chunk] = smax;
}

// ---------------- tree: OUT[m] = IN[2m+1] * IN[2m], adaptively renormalized ----------------
__global__ __launch_bounds__(256) void tree_k(const unsigned short* __restrict__ in,
                                              unsigned short* __restrict__ out,
                                              const int* __restrict__ sIn,
                                              int* __restrict__ sOut,
                                              const unsigned* __restrict__ mmIn,
                                              unsigned* __restrict__ mmOut) {
  __shared__ float Al[64][65];
  __shared__ float Bl[64][65];
  int m = blockIdx.x >> 6;
  int t = blockIdx.x & 63;
  int i0 = (t >> 3) * 64, j0 = (t & 7) * 64;
  const unsigned short* A = in + (size_t)(2 * m + 1) * 262144;  // later chunk (left)
  const unsigned short* B = in + (size_t)(2 * m) * 262144;      // earlier chunk (right)
  int tid = threadIdx.x;
  int ty = tid >> 4, tx = tid & 15;

  int ea = (int)(mmIn[2 * m + 1] >> 23) - 127;
  int eb = (int)(mmIn[2 * m] >> 23) - 127;
  ea = max(min(ea, 60), -60); eb = max(min(eb, 60), -60);
  float norm = __uint_as_float((unsigned)(127 - ea - eb) << 23);

  float acc[4][4] = {};
#pragma unroll 1
  for (int k0 = 0; k0 < 512; k0 += 64) {
    __syncthreads();
    int r = tid >> 2, cs = (tid & 3) * 16;
    const unsigned short* ap = A + (size_t)(i0 + r) * 512 + k0 + cs;
    const unsigned short* bp = B + (size_t)(k0 + r) * 512 + j0 + cs;
#pragma unroll
    for (int q = 0; q < 16; ++q) Al[r][cs + q] = bf2f(ap[q]);
#pragma unroll
    for (int q = 0; q < 16; ++q) Bl[r][cs + q] = bf2f(bp[q]);
    __syncthreads();
#pragma unroll 8
    for (int k = 0; k < 64; ++k) {
      float av[4], bv[4];
#pragma unroll
      for (int i = 0; i < 4; ++i) av[i] = Al[ty * 4 + i][k];
#pragma unroll
      for (int j = 0; j < 4; ++j) bv[j] = Bl[k][tx * 4 + j];
#pragma unroll
      for (int i = 0; i < 4; ++i)
#pragma unroll
        for (int j = 0; j < 4; ++j) acc[i][j] += av[i] * bv[j];
    }
  }
  float lmax = 0.f;
#pragma unroll
  for (int i = 0; i < 4; ++i)
#pragma unroll
    for (int j = 0; j < 4; ++j) {
      float v = acc[i][j] * norm;
      lmax = fmaxf(lmax, v);
      out[(size_t)m * 262144 + (size_t)(i0 + ty * 4 + i) * 512 + (j0 + tx * 4 + j)] = f2bf(v);
    }
#pragma unroll
  for (int off = 1; off < 64; off <<= 1) lmax = fmaxf(lmax, __shfl_xor(lmax, off, 64));
  if ((tid & 63) == 0) atomicMax(&mmOut[m], __float_as_uint(lmax));
  if (t == 0 && tid == 0) sOut[m] = sIn[2 * m] + sIn[2 * m + 1] + ea + eb;
}

// ---------------- final: forward = log(sum P_total) + scale*ln2; out = fwd - gold ----------------
__global__ __launch_bounds__(512) void final_k(const unsigned short* __restrict__ P,
                                               const int* __restrict__ sc,
                                               const float* __restrict__ gpart,
                                               float* __restrict__ outp) {
  __shared__ float red[512];
  float s = 0.f;
  for (int i = threadIdx.x; i < 262144; i += 512) s += bf2f(P[i]);
  red[threadIdx.x] = s;
  __syncthreads();
  for (int h = 256; h > 0; h >>= 1) {
    if ((int)threadIdx.x < h) red[threadIdx.x] += red[threadIdx.x + h];
    __syncthreads();
  }
  if (threadIdx.x == 0) {
    double gold = 0.0;
    for (int q = 0; q < 32; ++q) gold += (double)gpart[q];
    double fwd = log((double)red[0]) + 0.69314718055994530942 * (double)sc[0];
    outp[0] = (float)(fwd - gold);
  }
}

extern "C" void kernel_launch(void* const* d_in, const int* in_sizes, int n_in,
                              void* d_out, int out_size, void* d_ws, size_t ws_size,
                              hipStream_t stream) {
  const float* obs = (const float*)d_in[0];   // (K, T) f32
  const int* tags = (const int*)d_in[1];      // (T,) i32
  const float* tr = (const float*)d_in[2];    // (K, K) f32
  float* out = (float*)d_out;

  uint8_t* ws = (uint8_t*)d_ws;
  uint8_t* Ehat = ws + OFF_EHAT;
  float* gpart = (float*)(ws + OFF_GPART);
  int* sliceScales = (int*)(ws + OFF_SSCAL);
  int* sc = (int*)(ws + OFF_SC);           // 64 ints, per-level
  unsigned* mm = (unsigned*)(ws + OFF_MM); // 64 uints, per-level
  unsigned short* matsA = (unsigned short*)(ws + OFF_MATS_A);
  unsigned short* matsB = (unsigned short*)(ws + OFF_MATS_B);

  hipLaunchKernelGGL(init_k, dim3(1), dim3(64), 0, stream, mm);
  hipLaunchKernelGGL(prep_e8_k, dim3(256), dim3(512), 0, stream, tr, Ehat);
  hipLaunchKernelGGL(gold_k, dim3(32), dim3(1024), 0, stream, obs, tags, tr, gpart);
  hipLaunchKernelGGL(phase1_k, dim3(256), dim3(512), 0, stream, Ehat, obs, matsA, sliceScales);
  hipLaunchKernelGGL(repair_k, dim3(256), dim3(256), 0, stream, matsA, sliceScales, sc + 0, mm + 0);
  // tree: 32 -> 16 -> 8 -> 4 -> 2 -> 1 (alternating matsA/matsB)
  hipLaunchKernelGGL(tree_k, dim3(16 * 64), dim3(256), 0, stream, matsA, matsB, sc + 0,  sc + 32, mm + 0,  mm + 32);
  hipLaunchKernelGGL(tree_k, dim3(8 * 64),  dim3(256), 0, stream, matsB, matsA, sc + 32, sc + 48, mm + 32, mm + 48);
  hipLaunchKernelGGL(tree_k, dim3(4 * 64),  dim3(256), 0, stream, matsA, matsB, sc + 48, sc + 56, mm + 48, mm + 56);
  hipLaunchKernelGGL(tree_k, dim3(2 * 64),  dim3(256), 0, stream, matsB, matsA, sc + 56, sc + 60, mm + 56, mm + 60);
  hipLaunchKernelGGL(tree_k, dim3(1 * 64),  dim3(256), 0, stream, matsA, matsB, sc + 60, sc + 62, mm + 60, mm + 62);
  hipLaunchKernelGGL(final_k, dim3(1), dim3(512), 0, stream, matsB, sc + 62, gpart, out);
}

// Round 8
// 3492.176 us; speedup vs baseline: 2.2783x; 1.9830x over previous
//
#include <hip/hip_runtime.h>
#include <cstdint>
#include <cstddef>

// Problem constants
#define K_ 512
#define T_ 32768
#define L_STEPS 1024   // T_/32 chunks

// workspace layout (bytes) -- total ~26 MB
#define OFF_EHAT   0ul         // 512*512 fp8 = 262144
#define OFF_GPART  262144ul    // 32 f32 gold partials
#define OFF_SSCAL  262400ul    // 256 int slice scales
#define OFF_SC     263424ul    // 64 int: per-level mat scales
#define OFF_MM     263680ul    // 64 uint: per-level mat maxima (f32 bits)
#define OFF_MATS_A 1048576ul   // 32 mats * 512*512 bf16 = 16777216
#define OFF_MATS_B 17825792ul  // 16 mats bf16 = 8388608 (end 26214400)

typedef float f32x4 __attribute__((ext_vector_type(4)));
typedef int i32x8 __attribute__((ext_vector_type(8)));

#define PSTRIDE 520   // bytes per P-column row; conflict-free for b64 reads / b32 writes
#define FP8MAX 440.f  // clamp below e4m3 max(448) -> overflow saturates, never NaN

static __device__ __forceinline__ unsigned short f2bf(float x) {
  unsigned u = __float_as_uint(x);
  u += 0x7fffu + ((u >> 16) & 1u);
  return (unsigned short)(u >> 16);
}
static __device__ __forceinline__ float bf2f(unsigned short h) {
  return __uint_as_float(((unsigned)h) << 16);
}
// 32B LDS fragment via 4x ds_read_b64 (conflict-free at stride 520)
static __device__ __forceinline__ i32x8 lds_ld32(const uint8_t* p) {
  long long a = *(const long long*)p;
  long long b = *(const long long*)(p + 8);
  long long c = *(const long long*)(p + 16);
  long long d = *(const long long*)(p + 24);
  i32x8 r;
  r[0] = (int)a; r[1] = (int)(a >> 32);
  r[2] = (int)b; r[3] = (int)(b >> 32);
  r[4] = (int)c; r[5] = (int)(c >> 32);
  r[6] = (int)d; r[7] = (int)(d >> 32);
  return r;
}

// ---------------- init: zero the atomic-max slots ----------------
__global__ __launch_bounds__(64) void init_k(unsigned* __restrict__ mm) {
  mm[threadIdx.x] = 0u;
}

// ---------------- prep: Ehat = fp8_e4m3(exp(transitions)) ----------------
__global__ __launch_bounds__(512) void prep_e8_k(const float* __restrict__ tr,
                                                 uint8_t* __restrict__ Ehat) {
  int gid = blockIdx.x * 512 + threadIdx.x;
  int i2 = gid * 2;
  float a = fminf(__expf(tr[i2]), FP8MAX);
  float b = fminf(__expf(tr[i2 + 1]), FP8MAX);
  int w = __builtin_amdgcn_cvt_pk_fp8_f32(a, b, 0, false);
  *(unsigned short*)(Ehat + i2) = (unsigned short)(w & 0xffff);
}

// ---------------- gold score (exact f32, deterministic, 32 partials) ----------------
__global__ __launch_bounds__(1024) void gold_k(const float* __restrict__ obs,
                                               const int* __restrict__ tags,
                                               const float* __restrict__ tr,
                                               float* __restrict__ gpart) {
  __shared__ float red[1024];
  int i = blockIdx.x * 1024 + threadIdx.x;
  float s = 0.f;
  if (i < T_ - 1) {
    int cur = tags[i], nxt = tags[i + 1];
    s = tr[nxt * K_ + cur] + obs[(size_t)nxt * T_ + i];
  }
  red[threadIdx.x] = s;
  __syncthreads();
  for (int h = 512; h > 0; h >>= 1) {
    if ((int)threadIdx.x < h) red[threadIdx.x] += red[threadIdx.x + h];
    __syncthreads();
  }
  if (threadIdx.x == 0) gpart[blockIdx.x] = red[0];
}

// ---------------- phase 1: per-(chunk, 64-col slice) transfer matrix ----------------
// 8 waves; wave wv owns output rows 64wv..64wv+63. ONE barrier per step,
// double-buffered P (stride 520). Deferred power-of-2 renorm: sigma_t is known at
// the TOP of the step (predicted from step t-1's realized max; exact integer
// ledger; FP8MAX saturation makes mispredictions harmless). This enables a
// STREAMING epilogue: each 16-col block is scaled/converted/stored right after
// its kt-chain, so only 4 (not 16) accumulators are live -> no register spill
// (rounds 6/7 spilled ~10 regs/step; peak here ~190 of the 256/wave budget).
__global__ __launch_bounds__(512, 2)
void phase1_k(const uint8_t* __restrict__ Ehat, const float* __restrict__ obs,
              unsigned short* __restrict__ mats, int* __restrict__ sliceScales) {
  __shared__ __align__(16) uint8_t Plds[2][64 * PSTRIDE];  // 66560 B
  __shared__ float obs_lds[8][512];                        // 16384 B (exp(obs))
  __shared__ float pmax[2][512];                           // 4096 B

  const int tid = threadIdx.x;
  const int wv = tid >> 6;
  const int lane = tid & 63;
  const int l15 = lane & 15;
  const int g = lane >> 4;
  // XCD-aware remap: a chunk's 8 slices land on one XCD (shared L2 for obs)
  const int bid = blockIdx.x;
  const int chunk = 4 * (bid & 7) + (bid >> 6);
  const int slice = (bid >> 3) & 7;

  // E fragments for 16x16x128: lane holds A[row=l15][k=32g..32g+31] per (rt, kt).
  i32x8 ef[4][4];
#pragma unroll
  for (int rt = 0; rt < 4; ++rt)
#pragma unroll
    for (int kt = 0; kt < 4; ++kt)
      ef[rt][kt] = *(const i32x8*)(Ehat +
          ((64 * wv + 16 * rt + l15) * 512 + 128 * kt + 32 * g));

  // init P(buffer 0) = identity slice
  for (int i = tid; i < 64 * PSTRIDE / 4; i += 512) ((int*)Plds[0])[i] = 0;
  __syncthreads();
  if (tid < 64) {
    int gj = slice * 64 + tid;             // global state index of this column
    Plds[0][tid * PSTRIDE + gj] = 0x38;    // fp8 e4m3 1.0
  }
  __syncthreads();

  int accScale = 0;
  int sigPrev = 0, Sprev2 = 0;
  const int t0 = chunk * L_STEPS;
  const f32x4 z = (f32x4){0.f, 0.f, 0.f, 0.f};

  // obs prefetch registers (8 timesteps of this thread's row)
  float4 pf0, pf1;
  {
    const float4* sp = (const float4*)(obs + (size_t)tid * T_ + t0);
    pf0 = sp[0]; pf1 = sp[1];
  }

#pragma unroll 1
  for (int tl = 0; tl < L_STEPS; ++tl) {
    if ((tl & 7) == 0) {
      // stage exp(obs) so the epilogue never runs v_exp
      obs_lds[0][tid] = __expf(pf0.x); obs_lds[1][tid] = __expf(pf0.y);
      obs_lds[2][tid] = __expf(pf0.z); obs_lds[3][tid] = __expf(pf0.w);
      obs_lds[4][tid] = __expf(pf1.x); obs_lds[5][tid] = __expf(pf1.y);
      obs_lds[6][tid] = __expf(pf1.z); obs_lds[7][tid] = __expf(pf1.w);
      __syncthreads();
      int tn = t0 + tl + 8;
      if (tn >= T_) tn = 0;               // dummy for the last block
      const float4* sp = (const float4*)(obs + (size_t)tid * T_ + tn);
      pf0 = sp[0]; pf1 = sp[1];
    }

    // ---- sigma for THIS step, from step t-1's realized max (branchless) ----
    // tl==0: selects bootstrap -13; garbage pmax reads are discarded by selects
    // (Sprev2's tl==0 garbage is overwritten by tl==1's real S1 before use).
    {
      const float* pm = pmax[(tl & 1) ^ 1];
      float m = pm[lane];
#pragma unroll
      for (int q = 1; q < 8; ++q) m = fmaxf(m, pm[lane + (q << 6)]);
#pragma unroll
      for (int off = 1; off < 64; off <<= 1) m = fmaxf(m, __shfl_xor(m, off, 64));
      unsigned mb = __builtin_amdgcn_readfirstlane(__float_as_uint(m));
      int S1 = (int)((mb >> 23) & 255) - 127;
      S1 = min(max(S1, -60), 60);
      int gam = (tl <= 1) ? 16 : (S1 - sigPrev) - Sprev2;  // realized growth
      gam = min(max(gam, 2), 20);
      int sg = 3 - S1 - gam;               // target stored max ~2^3
      sg = min(max(sg, -60), 30);
      sg = (tl == 0) ? -13 : sg;
      Sprev2 = S1;
      sigPrev = sg;
    }
    accScale -= sigPrev;                   // TRUE = stored * 2^accScale
    const float scf = __uint_as_float((unsigned)(127 + sigPrev) << 23);

    // row factors exp(o_t[row]) * 2^sigma (16 regs, reused by all 4 col blocks)
    const int tl7 = tl & 7;
    float4 eoS[4];
#pragma unroll
    for (int rt = 0; rt < 4; ++rt) {
      float4 e4 = *(const float4*)&obs_lds[tl7][64 * wv + 16 * rt + 4 * g];
      eoS[rt].x = e4.x * scf; eoS[rt].y = e4.y * scf;
      eoS[rt].z = e4.z * scf; eoS[rt].w = e4.w * scf;
    }

    const uint8_t* bufR = Plds[tl & 1];
    uint8_t* bufW = Plds[(tl & 1) ^ 1];
    const uint8_t* baseR = bufR + l15 * PSTRIDE + 32 * g;
    float vmax = 0.f;

    // ---- 4 column blocks, each: 16-MFMA kt-chain then immediate epilogue ----
#pragma unroll
    for (int c = 0; c < 4; ++c) {
      const uint8_t* pb = baseR + c * (16 * PSTRIDE);
      f32x4 a0, a1, a2, a3;
      {
        i32x8 b = lds_ld32(pb);
        a0 = __builtin_amdgcn_mfma_scale_f32_16x16x128_f8f6f4(ef[0][0], b, z, 0, 0, 0, 0x7f7f7f7f, 0, 0x7f7f7f7f);
        a1 = __builtin_amdgcn_mfma_scale_f32_16x16x128_f8f6f4(ef[1][0], b, z, 0, 0, 0, 0x7f7f7f7f, 0, 0x7f7f7f7f);
        a2 = __builtin_amdgcn_mfma_scale_f32_16x16x128_f8f6f4(ef[2][0], b, z, 0, 0, 0, 0x7f7f7f7f, 0, 0x7f7f7f7f);
        a3 = __builtin_amdgcn_mfma_scale_f32_16x16x128_f8f6f4(ef[3][0], b, z, 0, 0, 0, 0x7f7f7f7f, 0, 0x7f7f7f7f);
      }
#pragma unroll
      for (int kt = 1; kt < 4; ++kt) {
        i32x8 b = lds_ld32(pb + 128 * kt);
        a0 = __builtin_amdgcn_mfma_scale_f32_16x16x128_f8f6f4(ef[0][kt], b, a0, 0, 0, 0, 0x7f7f7f7f, 0, 0x7f7f7f7f);
        a1 = __builtin_amdgcn_mfma_scale_f32_16x16x128_f8f6f4(ef[1][kt], b, a1, 0, 0, 0, 0x7f7f7f7f, 0, 0x7f7f7f7f);
        a2 = __builtin_amdgcn_mfma_scale_f32_16x16x128_f8f6f4(ef[2][kt], b, a2, 0, 0, 0, 0x7f7f7f7f, 0, 0x7f7f7f7f);
        a3 = __builtin_amdgcn_mfma_scale_f32_16x16x128_f8f6f4(ef[3][kt], b, a3, 0, 0, 0, 0x7f7f7f7f, 0, 0x7f7f7f7f);
      }
      // streaming epilogue for this 16-col block
      uint8_t* wbase = bufW + (16 * c + l15) * PSTRIDE + (64 * wv + 4 * g);
#pragma unroll
      for (int rt = 0; rt < 4; ++rt) {
        f32x4 a = (rt == 0) ? a0 : (rt == 1) ? a1 : (rt == 2) ? a2 : a3;
        float v0 = fminf(a[0] * eoS[rt].x, FP8MAX);
        float v1 = fminf(a[1] * eoS[rt].y, FP8MAX);
        float v2 = fminf(a[2] * eoS[rt].z, FP8MAX);
        float v3 = fminf(a[3] * eoS[rt].w, FP8MAX);
        vmax = fmaxf(vmax, fmaxf(fmaxf(v0, v1), fmaxf(v2, v3)));
        int w32 = __builtin_amdgcn_cvt_pk_fp8_f32(v0, v1, 0, false);
        w32 = __builtin_amdgcn_cvt_pk_fp8_f32(v2, v3, w32, true);
        *(int*)(wbase + 16 * rt) = w32;
      }
    }

    pmax[tl & 1][(wv << 6) + lane] = vmax;
    __syncthreads();
  }

  // write slice (bf16) to chunk matrix, row-major [i][j]; final P is in Plds[0]
  for (int cl = 0; cl < 64; ++cl) {
    float f = __builtin_amdgcn_cvt_f32_fp8((int)Plds[0][cl * PSTRIDE + tid], 0);
    mats[(size_t)chunk * 262144 + (size_t)tid * 512 + slice * 64 + cl] = f2bf(f);
  }
  if (tid == 0) sliceScales[chunk * 8 + slice] = accScale;
}

// ---------------- repair: harmonize the 8 slice scales of each chunk; record chunk max ----------------
__global__ __launch_bounds__(256) void repair_k(unsigned short* __restrict__ mats,
                                                const int* __restrict__ sliceScales,
                                                int* __restrict__ chunkScales,
                                                unsigned* __restrict__ mmL0) {
  int chunk = blockIdx.x >> 3, slice = blockIdx.x & 7;
  int smax = sliceScales[chunk * 8];
  for (int q = 1; q < 8; ++q) smax = max(smax, sliceScales[chunk * 8 + q]);
  int d = sliceScales[chunk * 8 + slice] - smax;   // <= 0
  float fac = exp2f((float)max(d, -126));
  float lmax = 0.f;
  for (int n = threadIdx.x; n < 512 * 64; n += 256) {
    int row = n >> 6, col = n & 63;
    size_t idx = (size_t)chunk * 262144 + (size_t)row * 512 + slice * 64 + col;
    float v = bf2f(mats[idx]) * fac;
    mats[idx] = f2bf(v);
    lmax = fmaxf(lmax, v);
  }
#pragma unroll
  for (int off = 1; off < 64; off <<= 1) lmax = fmaxf(lmax, __shfl_xor(lmax, off, 64));
  if ((threadIdx.x & 63) == 0) atomicMax(&mmL0[chunk], __float_as_uint(lmax));
  if (threadIdx.x == 0 && slice == 0) chunkScales[chunk] = smax;
}

// ---------------- tree: OUT[m] = IN[2m+1] * IN[2m], adaptively renormalized ----------------
__global__ __launch_bounds__(256) void tree_k(const unsigned short* __restrict__ in,
                                              unsigned short* __restrict__ out,
                                              const int* __restrict__ sIn,
                                              int* __restrict__ sOut,
                                              const unsigned* __restrict__ mmIn,
                                              unsigned* __restrict__ mmOut) {
  __shared__ float Al[64][65];
  __shared__ float Bl[64][65];
  int m = blockIdx.x >> 6;
  int t = blockIdx.x & 63;
  int i0 = (t >> 3) * 64, j0 = (t & 7) * 64;
  const unsigned short* A = in + (size_t)(2 * m + 1) * 262144;  // later chunk (left)
  const unsigned short* B = in + (size_t)(2 * m) * 262144;      // earlier chunk (right)
  int tid = threadIdx.x;
  int ty = tid >> 4, tx = tid & 15;

  int ea = (int)(mmIn[2 * m + 1] >> 23) - 127;
  int eb = (int)(mmIn[2 * m] >> 23) - 127;
  ea = max(min(ea, 60), -60); eb = max(min(eb, 60), -60);
  float norm = __uint_as_float((unsigned)(127 - ea - eb) << 23);

  float acc[4][4] = {};
#pragma unroll 1
  for (int k0 = 0; k0 < 512; k0 += 64) {
    __syncthreads();
    int r = tid >> 2, cs = (tid & 3) * 16;
    const unsigned short* ap = A + (size_t)(i0 + r) * 512 + k0 + cs;
    const unsigned short* bp = B + (size_t)(k0 + r) * 512 + j0 + cs;
#pragma unroll
    for (int q = 0; q < 16; ++q) Al[r][cs + q] = bf2f(ap[q]);
#pragma unroll
    for (int q = 0; q < 16; ++q) Bl[r][cs + q] = bf2f(bp[q]);
    __syncthreads();
#pragma unroll 8
    for (int k = 0; k < 64; ++k) {
      float av[4], bv[4];
#pragma unroll
      for (int i = 0; i < 4; ++i) av[i] = Al[ty * 4 + i][k];
#pragma unroll
      for (int j = 0; j < 4; ++j) bv[j] = Bl[k][tx * 4 + j];
#pragma unroll
      for (int i = 0; i < 4; ++i)
#pragma unroll
        for (int j = 0; j < 4; ++j) acc[i][j] += av[i] * bv[j];
    }
  }
  float lmax = 0.f;
#pragma unroll
  for (int i = 0; i < 4; ++i)
#pragma unroll
    for (int j = 0; j < 4; ++j) {
      float v = acc[i][j] * norm;
      lmax = fmaxf(lmax, v);
      out[(size_t)m * 262144 + (size_t)(i0 + ty * 4 + i) * 512 + (j0 + tx * 4 + j)] = f2bf(v);
    }
#pragma unroll
  for (int off = 1; off < 64; off <<= 1) lmax = fmaxf(lmax, __shfl_xor(lmax, off, 64));
  if ((tid & 63) == 0) atomicMax(&mmOut[m], __float_as_uint(lmax));
  if (t == 0 && tid == 0) sOut[m] = sIn[2 * m] + sIn[2 * m + 1] + ea + eb;
}

// ---------------- final: forward = log(sum P_total) + scale*ln2; out = fwd - gold ----------------
__global__ __launch_bounds__(512) void final_k(const unsigned short* __restrict__ P,
                                               const int* __restrict__ sc,
                                               const float* __restrict__ gpart,
                                               float* __restrict__ outp) {
  __shared__ float red[512];
  float s = 0.f;
  for (int i = threadIdx.x; i < 262144; i += 512) s += bf2f(P[i]);
  red[threadIdx.x] = s;
  __syncthreads();
  for (int h = 256; h > 0; h >>= 1) {
    if ((int)threadIdx.x < h) red[threadIdx.x] += red[threadIdx.x + h];
    __syncthreads();
  }
  if (threadIdx.x == 0) {
    double gold = 0.0;
    for (int q = 0; q < 32; ++q) gold += (double)gpart[q];
    double fwd = log((double)red[0]) + 0.69314718055994530942 * (double)sc[0];
    outp[0] = (float)(fwd - gold);
  }
}

extern "C" void kernel_launch(void* const* d_in, const int* in_sizes, int n_in,
                              void* d_out, int out_size, void* d_ws, size_t ws_size,
                              hipStream_t stream) {
  const float* obs = (const float*)d_in[0];   // (K, T) f32
  const int* tags = (const int*)d_in[1];      // (T,) i32
  const float* tr = (const float*)d_in[2];    // (K, K) f32
  float* out = (float*)d_out;

  uint8_t* ws = (uint8_t*)d_ws;
  uint8_t* Ehat = ws + OFF_EHAT;
  float* gpart = (float*)(ws + OFF_GPART);
  int* sliceScales = (int*)(ws + OFF_SSCAL);
  int* sc = (int*)(ws + OFF_SC);           // 64 ints, per-level
  unsigned* mm = (unsigned*)(ws + OFF_MM); // 64 uints, per-level
  unsigned short* matsA = (unsigned short*)(ws + OFF_MATS_A);
  unsigned short* matsB = (unsigned short*)(ws + OFF_MATS_B);

  hipLaunchKernelGGL(init_k, dim3(1), dim3(64), 0, stream, mm);
  hipLaunchKernelGGL(prep_e8_k, dim3(256), dim3(512), 0, stream, tr, Ehat);
  hipLaunchKernelGGL(gold_k, dim3(32), dim3(1024), 0, stream, obs, tags, tr, gpart);
  hipLaunchKernelGGL(phase1_k, dim3(256), dim3(512), 0, stream, Ehat, obs, matsA, sliceScales);
  hipLaunchKernelGGL(repair_k, dim3(256), dim3(256), 0, stream, matsA, sliceScales, sc + 0, mm + 0);
  // tree: 32 -> 16 -> 8 -> 4 -> 2 -> 1 (alternating matsA/matsB)
  hipLaunchKernelGGL(tree_k, dim3(16 * 64), dim3(256), 0, stream, matsA, matsB, sc + 0,  sc + 32, mm + 0,  mm + 32);
  hipLaunchKernelGGL(tree_k, dim3(8 * 64),  dim3(256), 0, stream, matsB, matsA, sc + 32, sc + 48, mm + 32, mm + 48);
  hipLaunchKernelGGL(tree_k, dim3(4 * 64),  dim3(256), 0, stream, matsA, matsB, sc + 48, sc + 56, mm + 48, mm + 56);
  hipLaunchKernelGGL(tree_k, dim3(2 * 64),  dim3(256), 0, stream, matsB, matsA, sc + 56, sc + 60, mm + 56, mm + 60);
  hipLaunchKernelGGL(tree_k, dim3(1 * 64),  dim3(256), 0, stream, matsA, matsB, sc + 60, sc + 62, mm + 60, mm + 62);
  hipLaunchKernelGGL(final_k, dim3(1), dim3(512), 0, stream, matsB, sc + 62, gpart, out);
}